// Round 3
// baseline (6469.791 us; speedup 1.0000x reference)
//
#include <hip/hip_runtime.h>

#define Bb 128
#define Nn 512
#define Ff 16
#define Hh 128
#define HIST 24
#define FW 24
#define Ee 8192
#define BN (Bb*Nn)      // 65536
#define NE (Bb*Ee)      // 1048576
#define THIST (HIST+FW) // 48
#define GM 16           // nodes per GRU block

// ---------------- CSR build ----------------
__global__ __launch_bounds__(256) void k_counts(const int* __restrict__ dst, int* __restrict__ counts){
  int e = blockIdx.x*256 + threadIdx.x;
  if (e < NE) atomicAdd(&counts[dst[e]], 1);
}

__global__ __launch_bounds__(256) void k_scan1(const int* __restrict__ counts, int* __restrict__ rowptr, int* __restrict__ bsum){
  __shared__ int ls[256];
  int tid = threadIdx.x, i = blockIdx.x*256 + tid;
  int c = counts[i];
  ls[tid] = c; __syncthreads();
  for (int off = 1; off < 256; off <<= 1){
    int v = (tid >= off) ? ls[tid-off] : 0;
    __syncthreads();
    ls[tid] += v; __syncthreads();
  }
  rowptr[i] = ls[tid] - c;              // block-local exclusive scan
  if (tid == 255) bsum[blockIdx.x] = ls[255];
}

__global__ __launch_bounds__(256) void k_scan2(int* __restrict__ bsum, int* __restrict__ rowptr){
  __shared__ int ls[256];
  int tid = threadIdx.x;
  int c = bsum[tid];
  ls[tid] = c; __syncthreads();
  for (int off = 1; off < 256; off <<= 1){
    int v = (tid >= off) ? ls[tid-off] : 0;
    __syncthreads();
    ls[tid] += v; __syncthreads();
  }
  bsum[tid] = ls[tid] - c;              // exclusive block offsets
  if (tid == 0) rowptr[BN] = NE;
}

// finalize rowptr, compute invdeg, zero counts (reused as scatter cursor)
__global__ __launch_bounds__(256) void k_scan3(const int* __restrict__ bsum, int* __restrict__ rowptr,
                                               int* __restrict__ counts, float* __restrict__ invdeg){
  int i = blockIdx.x*256 + threadIdx.x;
  rowptr[i] += bsum[blockIdx.x];
  invdeg[i] = 1.0f / fmaxf((float)counts[i], 1.0f);
  counts[i] = 0;
}

__global__ __launch_bounds__(256) void k_scatter(const int* __restrict__ src, const int* __restrict__ dst,
                                                 const int* __restrict__ rowptr, int* __restrict__ cursor,
                                                 int* __restrict__ srcs){
  int e = blockIdx.x*256 + threadIdx.x;
  if (e >= NE) return;
  int d = dst[e];
  int pos = rowptr[d] + atomicAdd(&cursor[d], 1);
  srcs[pos] = src[e];
}

// ---------------- precompute ----------------
__global__ __launch_bounds__(256) void k_init_xn(const float* __restrict__ pm, float* __restrict__ xn){
  int g = blockIdx.x*256 + threadIdx.x;
  if (g < BN){ int b = g>>9, n = g&511; xn[g] = pm[((size_t)b*HIST + (HIST-1))*Nn + n]; }
}

__global__ __launch_bounds__(256) void k_tih(const float* __restrict__ W_ih, float* __restrict__ Wt_ih){
  int i = blockIdx.x*256 + threadIdx.x;
  if (i < 384*18){ int j = i/18, c = i - j*18; Wt_ih[c*384 + j] = W_ih[i]; }
}

// sfeat[t][g] = feat_t[g]·W_nb[1:17], rootf[t][g] = feat_t[g]·W_root[1:17]
__global__ __launch_bounds__(256) void k_sfeat(const float* __restrict__ feature, const float* __restrict__ W_nb,
                                               const float* __restrict__ W_root,
                                               float* __restrict__ sfeat, float* __restrict__ rootf){
  int idx = blockIdx.x*256 + threadIdx.x;
  if (idx >= FW*BN) return;
  int t = idx >> 16, g = idx & 0xFFFF;
  int b = g>>9, n = g&511;
  const float* f = feature + (((size_t)b*THIST + HIST + t)*Nn + n)*Ff;
  float s = 0.f, r = 0.f;
  #pragma unroll
  for (int k = 0; k < Ff; k++){ float v = f[k]; s = fmaf(v, W_nb[1+k], s); r = fmaf(v, W_root[1+k], r); }
  sfeat[idx] = s; rootf[idx] = r;
}

// pre[t][d] = invdeg[d]*sum_src sfeat[t][src] + rootf[t][d] + b_nb   (in-place over rootf)
__global__ __launch_bounds__(256) void k_aggT(const int* __restrict__ rowptr, const int* __restrict__ srcs,
                                              const float* __restrict__ sfeat, const float* __restrict__ invdeg,
                                              const float* __restrict__ b_nb, float* __restrict__ pre){
  int idx = blockIdx.x*256 + threadIdx.x;
  if (idx >= FW*BN) return;
  int d = idx & 0xFFFF, t = idx >> 16;
  int e0 = rowptr[d], e1 = rowptr[d+1];
  const float* sf = sfeat + (size_t)t*BN;
  float s = 0.f;
  for (int e = e0; e < e1; e++) s += sf[srcs[e]];
  pre[idx] = invdeg[d]*s + pre[idx] + b_nb[0];
}

// ---------------- fused GCN-gate + GRU + readout ----------------
// 128 threads, GM nodes/block. Thread j owns gate rows j(r), j+128(z), j+256(n), h_new[j].
__global__ __launch_bounds__(128) void k_gru(
    float* __restrict__ h, const float* __restrict__ xn_in, float* __restrict__ xn_out,
    const float* __restrict__ pre_t, const float* __restrict__ invdeg,
    const float* __restrict__ feature, const int* __restrict__ rowptr, const int* __restrict__ srcs,
    const float* __restrict__ W_hh, const float* __restrict__ Wt_ih,
    const float* __restrict__ b_ih, const float* __restrict__ b_hh,
    const float* __restrict__ W_nb, const float* __restrict__ W_root,
    const float* __restrict__ W_out, const float* __restrict__ b_out,
    float* __restrict__ out, int t)
{
  __shared__ float h_lds[GM][Hh];
  __shared__ float x2_lds[GM][18];
  __shared__ float red[2][GM];
  __shared__ float sx_lds[GM];
  const int tid = threadIdx.x;
  const int g0 = blockIdx.x * GM;

  // SX gather via CSR: 8 threads per node, then 8-lane shuffle reduce
  {
    int m = tid >> 3, sub = tid & 7;
    int g = g0 + m;
    int e0 = rowptr[g], e1 = rowptr[g+1];
    float sx = 0.f;
    for (int e = e0 + sub; e < e1; e += 8) sx += xn_in[srcs[e]];
    sx += __shfl_xor(sx, 1); sx += __shfl_xor(sx, 2); sx += __shfl_xor(sx, 4);
    if (sub == 0) sx_lds[m] = sx;
  }

  #pragma unroll
  for (int m = 0; m < GM; m++) h_lds[m][tid] = h[(size_t)(g0+m)*Hh + tid];

  {
    int b = g0 >> 9, n0 = g0 & 511;
    const float* fb = feature + (((size_t)b*THIST + HIST + t)*Nn + n0)*Ff;
    for (int i = tid; i < GM*Ff; i += 128){
      int m = i >> 4, k = i & 15;
      x2_lds[m][1+k] = fb[i];
    }
  }
  __syncthreads();
  if (tid < GM){
    int g = g0 + tid;
    float xv = xn_in[g];
    float prea = pre_t[g] + invdeg[g]*W_nb[0]*sx_lds[tid] + W_root[0]*xv;
    x2_lds[tid][0]  = xv;
    x2_lds[tid][17] = 1.f/(1.f + expf(-prea));   // gcn gate
  }
  __syncthreads();

  float accR[GM], accZ[GM], accIN[GM], accHN[GM];
  {
    float bR = b_ih[tid] + b_hh[tid];
    float bZ = b_ih[128+tid] + b_hh[128+tid];
    float bI = b_ih[256+tid];
    float bH = b_hh[256+tid];
    #pragma unroll
    for (int m = 0; m < GM; m++){ accR[m]=bR; accZ[m]=bZ; accIN[m]=bI; accHN[m]=bH; }
  }

  // gh = W_hh @ h — W_hh is [384][128] row-major: direct float4 loads, L1-resident lines
  const float* wr_p = W_hh + (size_t)tid*Hh;
  const float* wz_p = W_hh + (size_t)(128+tid)*Hh;
  const float* wn_p = W_hh + (size_t)(256+tid)*Hh;
  for (int k = 0; k < Hh; k += 4){
    const float4 wr = *(const float4*)(wr_p + k);
    const float4 wz = *(const float4*)(wz_p + k);
    const float4 wn = *(const float4*)(wn_p + k);
    #pragma unroll
    for (int m = 0; m < GM; m++){
      const float4 hv = *(const float4*)&h_lds[m][k];
      accR[m]  = fmaf(wr.w,hv.w, fmaf(wr.z,hv.z, fmaf(wr.y,hv.y, fmaf(wr.x,hv.x, accR[m]))));
      accZ[m]  = fmaf(wz.w,hv.w, fmaf(wz.z,hv.z, fmaf(wz.y,hv.y, fmaf(wz.x,hv.x, accZ[m]))));
      accHN[m] = fmaf(wn.w,hv.w, fmaf(wn.z,hv.z, fmaf(wn.y,hv.y, fmaf(wn.x,hv.x, accHN[m]))));
    }
  }

  // gi = W_ih @ [xn, feat16, gcn]  (K=18, transposed weights, coalesced)
  #pragma unroll
  for (int c = 0; c < 18; c++){
    const float* wp = Wt_ih + (size_t)c*384 + tid;
    float wr = wp[0], wz = wp[128], wn = wp[256];
    #pragma unroll
    for (int m = 0; m < GM; m++){
      float xv = x2_lds[m][c];
      accR[m]  = fmaf(wr, xv, accR[m]);
      accZ[m]  = fmaf(wz, xv, accZ[m]);
      accIN[m] = fmaf(wn, xv, accIN[m]);
    }
  }

  const float wout = W_out[tid];
  float pout[GM];
  #pragma unroll
  for (int m = 0; m < GM; m++){
    float r  = 1.f/(1.f + expf(-accR[m]));
    float z  = 1.f/(1.f + expf(-accZ[m]));
    float nn = tanhf(fmaf(r, accHN[m], accIN[m]));
    float hold = h_lds[m][tid];
    float hv = (1.f - z)*nn + z*hold;
    h[(size_t)(g0+m)*Hh + tid] = hv;
    pout[m] = hv * wout;
  }

  int lane = tid & 63, wv = tid >> 6;
  #pragma unroll
  for (int m = 0; m < GM; m++){
    float v = pout[m];
    v += __shfl_down(v, 32); v += __shfl_down(v, 16); v += __shfl_down(v, 8);
    v += __shfl_down(v, 4);  v += __shfl_down(v, 2);  v += __shfl_down(v, 1);
    if (lane == 0) red[wv][m] = v;
  }
  __syncthreads();
  if (tid < GM){
    int g = g0 + tid, b = g>>9, n = g&511;
    float xv = red[0][tid] + red[1][tid] + b_out[0];
    xn_out[g] = xv;
    out[((size_t)b*FW + t)*Nn + n] = xv;
  }
}

extern "C" void kernel_launch(void* const* d_in, const int* in_sizes, int n_in,
                              void* d_out, int out_size, void* d_ws, size_t ws_size,
                              hipStream_t stream){
  const float* feature = (const float*)d_in[0];
  const float* pm25    = (const float*)d_in[1];
  const int*   eidx    = (const int*)d_in[2];
  const float* W_nb    = (const float*)d_in[3];
  const float* b_nb    = (const float*)d_in[4];
  const float* W_root  = (const float*)d_in[5];
  const float* W_ih    = (const float*)d_in[6];
  const float* W_hh    = (const float*)d_in[7];
  const float* b_ih    = (const float*)d_in[8];
  const float* b_hh    = (const float*)d_in[9];
  const float* W_out   = (const float*)d_in[10];
  const float* b_out   = (const float*)d_in[11];
  float* out = (float*)d_out;
  const int* src = eidx;
  const int* dst = eidx + NE;

  char* wsp = (char*)d_ws;
  float* invdeg = (float*)wsp; wsp += (size_t)BN*4;
  float* xn_a   = (float*)wsp; wsp += (size_t)BN*4;
  float* xn_b   = (float*)wsp; wsp += (size_t)BN*4;
  int*   counts = (int*)wsp;   wsp += (size_t)BN*4;       // doubles as scatter cursor
  int*   rowptr = (int*)wsp;   wsp += (size_t)(BN+64)*4;
  int*   bsum   = (int*)wsp;   wsp += 256*4;
  int*   srcs   = (int*)wsp;   wsp += (size_t)NE*4;
  float* sfeat  = (float*)wsp; wsp += (size_t)FW*BN*4;
  float* pre    = (float*)wsp; wsp += (size_t)FW*BN*4;    // rootf, then in-place pre
  float* Wt_ih  = (float*)wsp; wsp += 18*384*4;
  float* hbuf   = (float*)wsp; wsp += (size_t)BN*Hh*4;

  hipMemsetAsync(counts, 0, BN*sizeof(int), stream);
  hipMemsetAsync(hbuf, 0, (size_t)BN*Hh*sizeof(float), stream);

  k_counts <<<NE/256, 256, 0, stream>>>(dst, counts);
  k_scan1  <<<BN/256, 256, 0, stream>>>(counts, rowptr, bsum);
  k_scan2  <<<1, 256, 0, stream>>>(bsum, rowptr);
  k_scan3  <<<BN/256, 256, 0, stream>>>(bsum, rowptr, counts, invdeg);
  k_scatter<<<NE/256, 256, 0, stream>>>(src, dst, rowptr, counts, srcs);

  k_init_xn<<<BN/256, 256, 0, stream>>>(pm25, xn_a);
  k_tih    <<<(384*18 + 255)/256, 256, 0, stream>>>(W_ih, Wt_ih);
  k_sfeat  <<<(FW*BN)/256, 256, 0, stream>>>(feature, W_nb, W_root, sfeat, pre);
  k_aggT   <<<(FW*BN)/256, 256, 0, stream>>>(rowptr, srcs, sfeat, invdeg, b_nb, pre);

  float* xa = xn_a; float* xb = xn_b;
  for (int t = 0; t < FW; t++){
    k_gru<<<BN/GM, 128, 0, stream>>>(hbuf, xa, xb, pre + (size_t)t*BN, invdeg,
                                     feature, rowptr, srcs, W_hh, Wt_ih, b_ih, b_hh,
                                     W_nb, W_root, W_out, b_out, out, t);
    float* tmp = xa; xa = xb; xb = tmp;
  }
}

// Round 5
// 1471.931 us; speedup vs baseline: 4.3954x; 4.3954x over previous
//
#include <hip/hip_runtime.h>

typedef short bf16x8 __attribute__((ext_vector_type(8)));
typedef float f32x4  __attribute__((ext_vector_type(4)));

#define Bb 128
#define Nn 512
#define Ff 16
#define Hh 128
#define HIST 24
#define FW 24
#define Ee 8192
#define BN (Bb*Nn)      // 65536
#define NE (Bb*Ee)      // 1048576
#define THIST (HIST+FW) // 48
#define MB 64           // nodes per GRU block
#define NSLOT 20        // K=160 -> 20 slots of 8 bf16
#define WPN (4*4*2*NSLOT*16*8)   // 81920 bf16 elements

__device__ __forceinline__ unsigned short f2bfu(float x){
  union { float f; unsigned u; } v; v.f = x;
  unsigned r = v.u + 0x7FFFu + ((v.u >> 16) & 1u);
  return (unsigned short)(r >> 16);
}
__device__ __forceinline__ float sigm(float x){ return 1.f/(1.f + __expf(-x)); }
__device__ __forceinline__ float tanh_f(float x){ return 1.f - 2.f/(__expf(2.f*x) + 1.f); }

// ---------------- CSR build ----------------
__global__ __launch_bounds__(256) void k_counts(const int* __restrict__ dst, int* __restrict__ counts){
  int e = blockIdx.x*256 + threadIdx.x;
  if (e < NE) atomicAdd(&counts[dst[e]], 1);
}

__global__ __launch_bounds__(256) void k_scan1(const int* __restrict__ counts, int* __restrict__ rowptr, int* __restrict__ bsum){
  __shared__ int ls[256];
  int tid = threadIdx.x, i = blockIdx.x*256 + tid;
  int c = counts[i];
  ls[tid] = c; __syncthreads();
  for (int off = 1; off < 256; off <<= 1){
    int v = (tid >= off) ? ls[tid-off] : 0;
    __syncthreads();
    ls[tid] += v; __syncthreads();
  }
  rowptr[i] = ls[tid] - c;
  if (tid == 255) bsum[blockIdx.x] = ls[255];
}

__global__ __launch_bounds__(256) void k_scan2(int* __restrict__ bsum, int* __restrict__ rowptr){
  __shared__ int ls[256];
  int tid = threadIdx.x;
  int c = bsum[tid];
  ls[tid] = c; __syncthreads();
  for (int off = 1; off < 256; off <<= 1){
    int v = (tid >= off) ? ls[tid-off] : 0;
    __syncthreads();
    ls[tid] += v; __syncthreads();
  }
  bsum[tid] = ls[tid] - c;
  if (tid == 0) rowptr[BN] = NE;
}

__global__ __launch_bounds__(256) void k_scan3(const int* __restrict__ bsum, int* __restrict__ rowptr,
                                               int* __restrict__ counts, float* __restrict__ invdeg){
  int i = blockIdx.x*256 + threadIdx.x;
  rowptr[i] += bsum[blockIdx.x];
  invdeg[i] = 1.0f / fmaxf((float)counts[i], 1.0f);
  counts[i] = 0;
}

__global__ __launch_bounds__(256) void k_scatter(const int* __restrict__ src, const int* __restrict__ dst,
                                                 const int* __restrict__ rowptr, int* __restrict__ cursor,
                                                 int* __restrict__ srcs){
  int e = blockIdx.x*256 + threadIdx.x;
  if (e >= NE) return;
  int d = dst[e];
  int pos = rowptr[d] + atomicAdd(&cursor[d], 1);
  srcs[pos] = src[e];
}

// ---------------- precompute ----------------
__global__ __launch_bounds__(256) void k_init_xn(const float* __restrict__ pm, float* __restrict__ xn){
  int g = blockIdx.x*256 + threadIdx.x;
  if (g < BN){ int b = g>>9, n = g&511; xn[g] = pm[((size_t)b*HIST + (HIST-1))*Nn + n]; }
}

// Pack Wbig[512 cols][K=160] into B-fragment order for mfma_f32_16x16x32_bf16.
// flat idx = ((((g*4 + w)*2 + nt)*20 + slot)*16 + c)*8 + j
// gate col = w*32 + nt*16 + c ; k = slot*8 + j
// K layout: k in [0,18) = x2 = [xn, f0..f15, gcn]; [18,32) = 0; [32,160) = h
__global__ __launch_bounds__(256) void k_wpack(const float* __restrict__ W_ih, const float* __restrict__ W_hh,
                                               unsigned short* __restrict__ Wpack){
  int idx = blockIdx.x*256 + threadIdx.x;
  if (idx >= WPN) return;
  int j = idx & 7;
  int r = idx >> 3;
  int c = r & 15; r >>= 4;
  int slot = r % NSLOT; r /= NSLOT;
  int nt = r & 1; r >>= 1;
  int w = r & 3; int g = r >> 2;
  int k = slot*8 + j;
  int col = w*32 + nt*16 + c;       // 0..127
  float v = 0.f;
  if (g == 0 || g == 1){            // r, z : fused x2 + h
    int row = (g == 0) ? col : 128 + col;
    if (k < 32){ if (k < 18) v = W_ih[row*18 + k]; }
    else v = W_hh[(size_t)row*128 + (k-32)];
  } else if (g == 2){               // i_n : x2 only
    if (k < 18) v = W_ih[(256+col)*18 + k];
  } else {                          // h_n : h only
    if (k >= 32) v = W_hh[(size_t)(256+col)*128 + (k-32)];
  }
  Wpack[idx] = f2bfu(v);
}

// sfeat[t][g] = feat_t[g]·W_nb[1:17], rootf[t][g] = feat_t[g]·W_root[1:17]
__global__ __launch_bounds__(256) void k_sfeat(const float* __restrict__ feature, const float* __restrict__ W_nb,
                                               const float* __restrict__ W_root,
                                               float* __restrict__ sfeat, float* __restrict__ rootf){
  int idx = blockIdx.x*256 + threadIdx.x;
  if (idx >= FW*BN) return;
  int t = idx >> 16, g = idx & 0xFFFF;
  int b = g>>9, n = g&511;
  const float* f = feature + (((size_t)b*THIST + HIST + t)*Nn + n)*Ff;
  float s = 0.f, r = 0.f;
  #pragma unroll
  for (int k = 0; k < Ff; k++){ float v = f[k]; s = fmaf(v, W_nb[1+k], s); r = fmaf(v, W_root[1+k], r); }
  sfeat[idx] = s; rootf[idx] = r;
}

// pre[t][d] = invdeg[d]*sum_src sfeat[t][src] + rootf[t][d] + b_nb   (in-place over rootf)
__global__ __launch_bounds__(256) void k_aggT(const int* __restrict__ rowptr, const int* __restrict__ srcs,
                                              const float* __restrict__ sfeat, const float* __restrict__ invdeg,
                                              const float* __restrict__ b_nb, float* __restrict__ pre){
  int idx = blockIdx.x*256 + threadIdx.x;
  if (idx >= FW*BN) return;
  int d = idx & 0xFFFF, t = idx >> 16;
  int e0 = rowptr[d], e1 = rowptr[d+1];
  const float* sf = sfeat + (size_t)t*BN;
  float s = 0.f;
  for (int e = e0; e < e1; e++) s += sf[srcs[e]];
  pre[idx] = invdeg[d]*s + pre[idx] + b_nb[0];
}

// ---------------- fused MFMA GRU step ----------------
// 256 threads = 4 waves, MB=64 nodes/block. One GEMM: [64 x K160] x [K160 x 512]
// wave w owns cols [w*32, w*32+32) of each of the 4 gate groups -> epilogue register-local.
__global__ __launch_bounds__(256, 2) void k_gru(
    float* __restrict__ h, unsigned short* __restrict__ hbf,
    const float* __restrict__ xn_in, float* __restrict__ xn_out,
    const float* __restrict__ pre_t, const float* __restrict__ invdeg,
    const float* __restrict__ feature, const int* __restrict__ rowptr, const int* __restrict__ srcs,
    const unsigned short* __restrict__ Wpack,
    const float* __restrict__ b_ih, const float* __restrict__ b_hh,
    const float* __restrict__ W_nb, const float* __restrict__ W_root,
    const float* __restrict__ W_out, const float* __restrict__ b_out,
    float* __restrict__ out, int t)
{
  __shared__ __align__(16) short A_lds[NSLOT*MB*8];   // 20 KB, slot=k/8, pos=(row+slot)&63
  __shared__ float gcn_lds[MB], xn_lds[MB];
  __shared__ float xnpart[4][MB];
  const int tid = threadIdx.x;
  const int g0 = blockIdx.x * MB;

  // --- SX gather (4 threads/node) + gcn gate ---
  {
    int m = tid >> 2, sub = tid & 3;
    int g = g0 + m;
    int e1 = rowptr[g+1];
    float sx = 0.f;
    for (int e = rowptr[g] + sub; e < e1; e += 4) sx += xn_in[srcs[e]];
    sx += __shfl_xor(sx, 1); sx += __shfl_xor(sx, 2);
    if (sub == 0){
      float xv = xn_in[g];
      float prea = pre_t[g] + invdeg[g]*W_nb[0]*sx + W_root[0]*xv;
      xn_lds[m] = xv;
      gcn_lds[m] = sigm(prea);
    }
  }
  __syncthreads();

  // --- stage x2 (slots 0..3): [xn, f0..f15, gcn, 0...] ---
  if (tid < MB){
    int row = tid;
    int b = g0 >> 9, n = (g0 & 511) + row;
    const float4* fb = (const float4*)(feature + (((size_t)b*THIST + HIST + t)*Nn + n)*Ff);
    float4 f0 = fb[0], f1 = fb[1], f2 = fb[2], f3 = fb[3];
    short v[32];
    v[0] = (short)f2bfu(xn_lds[row]);
    v[1] = (short)f2bfu(f0.x); v[2] = (short)f2bfu(f0.y); v[3] = (short)f2bfu(f0.z); v[4] = (short)f2bfu(f0.w);
    v[5] = (short)f2bfu(f1.x); v[6] = (short)f2bfu(f1.y); v[7] = (short)f2bfu(f1.z); v[8] = (short)f2bfu(f1.w);
    v[9] = (short)f2bfu(f2.x); v[10]= (short)f2bfu(f2.y); v[11]= (short)f2bfu(f2.z); v[12]= (short)f2bfu(f2.w);
    v[13]= (short)f2bfu(f3.x); v[14]= (short)f2bfu(f3.y); v[15]= (short)f2bfu(f3.z); v[16]= (short)f2bfu(f3.w);
    v[17]= (short)f2bfu(gcn_lds[row]);
    #pragma unroll
    for (int k = 18; k < 32; k++) v[k] = 0;
    #pragma unroll
    for (int s = 0; s < 4; s++){
      int pos = (row + s) & 63;
      *(bf16x8*)&A_lds[(s*MB + pos)*8] = *(bf16x8*)&v[s*8];
    }
  }
  // --- stage h (slots 4..19) from hbf, coalesced global, rotated LDS ---
  for (int i = tid; i < MB*16; i += 256){
    int kg = i & 15, row = i >> 4;
    bf16x8 hv = *(const bf16x8*)&hbf[(size_t)(g0+row)*Hh + kg*8];
    int s = 4 + kg, pos = (row + s) & 63;
    *(bf16x8*)&A_lds[(s*MB + pos)*8] = hv;
  }
  __syncthreads();

  const int l = tid & 63, w = tid >> 6;
  const int c = l & 15, lg = l >> 4;

  f32x4 acc[4][4][2] = {};   // [gate][m][nt]
  #pragma unroll
  for (int kk = 0; kk < 5; kk++){
    bf16x8 a[4];
    #pragma unroll
    for (int m = 0; m < 4; m++){
      int s = kk*4 + lg, row = m*16 + c, pos = (row + s) & 63;
      a[m] = *(const bf16x8*)&A_lds[(s*MB + pos)*8];
    }
    #pragma unroll
    for (int g = 0; g < 4; g++){
      #pragma unroll
      for (int nt = 0; nt < 2; nt++){
        const bf16x8 bv = *(const bf16x8*)&Wpack[ (size_t)((((g*4+w)*2+nt)*NSLOT + kk*4 + lg)*16 + c)*8 ];
        #pragma unroll
        for (int m = 0; m < 4; m++)
          acc[g][m][nt] = __builtin_amdgcn_mfma_f32_16x16x32_bf16(a[m], bv, acc[g][m][nt], 0, 0, 0);
      }
    }
  }

  // --- epilogue: register-local GRU elementwise ---
  float bR[2], bZ[2], bI[2], bH[2], wo[2]; int jj[2];
  #pragma unroll
  for (int nt = 0; nt < 2; nt++){
    int j = w*32 + nt*16 + c; jj[nt] = j;
    bR[nt] = b_ih[j] + b_hh[j];
    bZ[nt] = b_ih[128+j] + b_hh[128+j];
    bI[nt] = b_ih[256+j];
    bH[nt] = b_hh[256+j];
    wo[nt] = W_out[j];
  }
  float psum[4][4] = {};   // [m][q] partial xn per row
  #pragma unroll
  for (int m = 0; m < 4; m++){
    #pragma unroll
    for (int nt = 0; nt < 2; nt++){
      #pragma unroll
      for (int q = 0; q < 4; q++){
        int row = 16*m + lg*4 + q;
        size_t off = (size_t)(g0 + row)*Hh + jj[nt];
        float hold = h[off];
        float rr = sigm(acc[0][m][nt][q] + bR[nt]);
        float zz = sigm(acc[1][m][nt][q] + bZ[nt]);
        float nn = tanh_f(acc[2][m][nt][q] + bI[nt] + rr*(acc[3][m][nt][q] + bH[nt]));
        float hv = (1.f - zz)*nn + zz*hold;
        h[off] = hv;
        hbf[off] = f2bfu(hv);
        psum[m][q] = fmaf(hv, wo[nt], psum[m][q]);
      }
    }
  }
  // reduce over the 16 cols held by this lane group (and both nt, already summed)
  #pragma unroll
  for (int mask = 1; mask < 16; mask <<= 1){
    #pragma unroll
    for (int m = 0; m < 4; m++)
      #pragma unroll
      for (int q = 0; q < 4; q++)
        psum[m][q] += __shfl_xor(psum[m][q], mask);
  }
  if (c == 0){
    #pragma unroll
    for (int m = 0; m < 4; m++)
      #pragma unroll
      for (int q = 0; q < 4; q++)
        xnpart[w][16*m + lg*4 + q] = psum[m][q];
  }
  __syncthreads();
  if (tid < MB){
    int row = tid, g = g0 + row, b = g >> 9, n = g & 511;
    float xv = xnpart[0][row] + xnpart[1][row] + xnpart[2][row] + xnpart[3][row] + b_out[0];
    xn_out[g] = xv;
    out[((size_t)b*FW + t)*Nn + n] = xv;
  }
}

extern "C" void kernel_launch(void* const* d_in, const int* in_sizes, int n_in,
                              void* d_out, int out_size, void* d_ws, size_t ws_size,
                              hipStream_t stream){
  const float* feature = (const float*)d_in[0];
  const float* pm25    = (const float*)d_in[1];
  const int*   eidx    = (const int*)d_in[2];
  const float* W_nb    = (const float*)d_in[3];
  const float* b_nb    = (const float*)d_in[4];
  const float* W_root  = (const float*)d_in[5];
  const float* W_ih    = (const float*)d_in[6];
  const float* W_hh    = (const float*)d_in[7];
  const float* b_ih    = (const float*)d_in[8];
  const float* b_hh    = (const float*)d_in[9];
  const float* W_out   = (const float*)d_in[10];
  const float* b_out   = (const float*)d_in[11];
  float* out = (float*)d_out;
  const int* src = eidx;
  const int* dst = eidx + NE;

  char* wsp = (char*)d_ws;
  float* invdeg = (float*)wsp; wsp += (size_t)BN*4;
  float* xn_a   = (float*)wsp; wsp += (size_t)BN*4;
  float* xn_b   = (float*)wsp; wsp += (size_t)BN*4;
  int*   counts = (int*)wsp;   wsp += (size_t)BN*4;
  int*   rowptr = (int*)wsp;   wsp += (size_t)(BN+64)*4;
  int*   bsum   = (int*)wsp;   wsp += 256*4;
  int*   srcs   = (int*)wsp;   wsp += (size_t)NE*4;
  float* sfeat  = (float*)wsp; wsp += (size_t)FW*BN*4;
  float* pre    = (float*)wsp; wsp += (size_t)FW*BN*4;
  unsigned short* Wpack = (unsigned short*)wsp; wsp += (size_t)WPN*2;
  float* hbuf   = (float*)wsp; wsp += (size_t)BN*Hh*4;
  unsigned short* hbf = (unsigned short*)wsp; wsp += (size_t)BN*Hh*2;

  hipMemsetAsync(counts, 0, BN*sizeof(int), stream);
  hipMemsetAsync(hbuf, 0, (size_t)BN*Hh*sizeof(float), stream);
  hipMemsetAsync(hbf, 0, (size_t)BN*Hh*sizeof(unsigned short), stream);

  k_counts <<<NE/256, 256, 0, stream>>>(dst, counts);
  k_scan1  <<<BN/256, 256, 0, stream>>>(counts, rowptr, bsum);
  k_scan2  <<<1, 256, 0, stream>>>(bsum, rowptr);
  k_scan3  <<<BN/256, 256, 0, stream>>>(bsum, rowptr, counts, invdeg);
  k_scatter<<<NE/256, 256, 0, stream>>>(src, dst, rowptr, counts, srcs);

  k_init_xn<<<BN/256, 256, 0, stream>>>(pm25, xn_a);
  k_wpack  <<<(WPN+255)/256, 256, 0, stream>>>(W_ih, W_hh, Wpack);
  k_sfeat  <<<(FW*BN)/256, 256, 0, stream>>>(feature, W_nb, W_root, sfeat, pre);
  k_aggT   <<<(FW*BN)/256, 256, 0, stream>>>(rowptr, srcs, sfeat, invdeg, b_nb, pre);

  float* xa = xn_a; float* xb = xn_b;
  for (int t = 0; t < FW; t++){
    k_gru<<<BN/MB, 256, 0, stream>>>(hbuf, hbf, xa, xb, pre + (size_t)t*BN, invdeg,
                                     feature, rowptr, srcs, Wpack, b_ih, b_hh,
                                     W_nb, W_root, W_out, b_out, out, t);
    float* tmp = xa; xa = xb; xb = tmp;
  }
}

// Round 6
// 1183.102 us; speedup vs baseline: 5.4685x; 1.2441x over previous
//
#include <hip/hip_runtime.h>

typedef short bf16x8 __attribute__((ext_vector_type(8)));
typedef float f32x4  __attribute__((ext_vector_type(4)));

#define Bb 128
#define Nn 512
#define Ff 16
#define Hh 128
#define HIST 24
#define FW 24
#define Ee 8192
#define BN (Bb*Nn)      // 65536
#define NE (Bb*Ee)      // 1048576
#define THIST (HIST+FW) // 48
#define MB 64           // nodes per GRU block
#define NSLOT 20        // K=160 -> 20 slots of 8 bf16
#define WPN (4*4*2*NSLOT*16*8)   // 81920 bf16 elements

__device__ __forceinline__ unsigned short f2bfu(float x){
  union { float f; unsigned u; } v; v.f = x;
  unsigned r = v.u + 0x7FFFu + ((v.u >> 16) & 1u);
  return (unsigned short)(r >> 16);
}
__device__ __forceinline__ float sigm(float x){ return 1.f/(1.f + __expf(-x)); }
__device__ __forceinline__ float tanh_f(float x){ return 1.f - 2.f/(__expf(2.f*x) + 1.f); }

// ---------------- one-shot local CSR (graph is identical across batches) ----------------
// edges e<Ee have src=eidx[e], dst=eidx[NE+e], both in [0,512)
__global__ __launch_bounds__(512) void k_csr(const int* __restrict__ eidx, int* __restrict__ rowptrL,
                                             int* __restrict__ srcsL, float* __restrict__ invdegL){
  __shared__ int cnt[512];
  __shared__ int scan[512];
  int tid = threadIdx.x;
  cnt[tid] = 0;
  __syncthreads();
  for (int e = tid; e < Ee; e += 512) atomicAdd(&cnt[eidx[NE + e]], 1);
  __syncthreads();
  int c = cnt[tid];
  scan[tid] = c;
  __syncthreads();
  for (int off = 1; off < 512; off <<= 1){
    int v = (tid >= off) ? scan[tid-off] : 0;
    __syncthreads();
    scan[tid] += v;
    __syncthreads();
  }
  int excl = scan[tid] - c;
  rowptrL[tid] = excl;
  if (tid == 0) rowptrL[512] = Ee;
  invdegL[tid] = 1.0f / fmaxf((float)c, 1.0f);
  __syncthreads();
  scan[tid] = excl;   // now exclusive offsets
  cnt[tid] = 0;       // cursor
  __syncthreads();
  for (int e = tid; e < Ee; e += 512){
    int d = eidx[NE + e];
    int pos = scan[d] + atomicAdd(&cnt[d], 1);
    srcsL[pos] = eidx[e];
  }
}

// ---------------- precompute ----------------
__global__ __launch_bounds__(256) void k_init_xn(const float* __restrict__ pm, float* __restrict__ xn){
  int g = blockIdx.x*256 + threadIdx.x;
  if (g < BN){ int b = g>>9, n = g&511; xn[g] = pm[((size_t)b*HIST + (HIST-1))*Nn + n]; }
}

// Pack Wbig[512 cols][K=160] into B-fragment order for mfma_f32_16x16x32_bf16.
// flat idx = ((((g*4 + w)*2 + nt)*20 + slot)*16 + c)*8 + j
// gate col = w*32 + nt*16 + c ; k = slot*8 + j
// K layout: k in [0,18) = x2 = [xn, f0..f15, gcn]; [18,32) = 0; [32,160) = h
__global__ __launch_bounds__(256) void k_wpack(const float* __restrict__ W_ih, const float* __restrict__ W_hh,
                                               unsigned short* __restrict__ Wpack){
  int idx = blockIdx.x*256 + threadIdx.x;
  if (idx >= WPN) return;
  int j = idx & 7;
  int r = idx >> 3;
  int c = r & 15; r >>= 4;
  int slot = r % NSLOT; r /= NSLOT;
  int nt = r & 1; r >>= 1;
  int w = r & 3; int g = r >> 2;
  int k = slot*8 + j;
  int col = w*32 + nt*16 + c;       // 0..127
  float v = 0.f;
  if (g == 0 || g == 1){            // r, z : fused x2 + h
    int row = (g == 0) ? col : 128 + col;
    if (k < 32){ if (k < 18) v = W_ih[row*18 + k]; }
    else v = W_hh[(size_t)row*128 + (k-32)];
  } else if (g == 2){               // i_n : x2 only
    if (k < 18) v = W_ih[(256+col)*18 + k];
  } else {                          // h_n : h only
    if (k >= 32) v = W_hh[(size_t)(256+col)*128 + (k-32)];
  }
  Wpack[idx] = f2bfu(v);
}

// sfeat[t][g] = feat·W_nb[1:17]; rootf[t][g] = feat·W_root[1:17]; xfb[t][g][16] = bf16(feat)
__global__ __launch_bounds__(256) void k_sfeat(const float* __restrict__ feature, const float* __restrict__ W_nb,
                                               const float* __restrict__ W_root,
                                               float* __restrict__ sfeat, float* __restrict__ rootf,
                                               unsigned short* __restrict__ xfb){
  int idx = blockIdx.x*256 + threadIdx.x;
  if (idx >= FW*BN) return;
  int t = idx >> 16, g = idx & 0xFFFF;
  int b = g>>9, n = g&511;
  const float* f = feature + (((size_t)b*THIST + HIST + t)*Nn + n)*Ff;
  unsigned short xv[16];
  float s = 0.f, r = 0.f;
  #pragma unroll
  for (int k = 0; k < Ff; k++){
    float v = f[k];
    s = fmaf(v, W_nb[1+k], s); r = fmaf(v, W_root[1+k], r);
    xv[k] = f2bfu(v);
  }
  sfeat[idx] = s; rootf[idx] = r;
  *(bf16x8*)&xfb[(size_t)idx*16]     = *(bf16x8*)&xv[0];
  *(bf16x8*)&xfb[(size_t)idx*16 + 8] = *(bf16x8*)&xv[8];
}

// pre[t][d] = invdegL[n]*sum_src sfeat[t][src] + rootf[t][d] + b_nb   (in-place over rootf)
__global__ __launch_bounds__(256) void k_aggT(const int* __restrict__ rowptrL, const int* __restrict__ srcsL,
                                              const float* __restrict__ sfeat, const float* __restrict__ invdegL,
                                              const float* __restrict__ b_nb, float* __restrict__ pre){
  int idx = blockIdx.x*256 + threadIdx.x;
  if (idx >= FW*BN) return;
  int g = idx & 0xFFFF, t = idx >> 16;
  int n = g & 511, b = g >> 9;
  int e0 = rowptrL[n], e1 = rowptrL[n+1];
  const float* sf = sfeat + (size_t)t*BN + (size_t)b*Nn;
  float s = 0.f;
  for (int e = e0; e < e1; e++) s += sf[srcsL[e]];
  pre[idx] = invdegL[n]*s + pre[idx] + b_nb[0];
}

// ---------------- fused MFMA GRU step ----------------
// 256 threads = 4 waves, MB=64 nodes/block. One GEMM: [64 x K160] x [K160 x 512]
// wave w owns cols [w*32, w*32+32) of each of the 4 gate groups -> epilogue register-local.
__global__ __launch_bounds__(256, 2) void k_gru(
    float* __restrict__ h,
    const float* __restrict__ xn_in, float* __restrict__ xn_out,
    const float* __restrict__ pre_t, const float* __restrict__ invdegL,
    const unsigned short* __restrict__ xfb_t,
    const int* __restrict__ rowptrL, const int* __restrict__ srcsL,
    const unsigned short* __restrict__ Wpack,
    const float* __restrict__ b_ih, const float* __restrict__ b_hh,
    const float* __restrict__ W_nb, const float* __restrict__ W_root,
    const float* __restrict__ W_out, const float* __restrict__ b_out,
    float* __restrict__ out, int t)
{
  __shared__ __align__(16) short A_lds[NSLOT*MB*8];   // 20 KB, slot=k/8, pos=(row+slot)&63
  __shared__ float gcn_lds[MB], xn_lds[MB];
  __shared__ float xnpart[4][MB];
  const int tid = threadIdx.x;
  const int g0 = blockIdx.x * MB;
  const int b = g0 >> 9, n0 = g0 & 511;

  // --- SX gather via local CSR (4 threads/node) + gcn gate ---
  {
    int m = tid >> 2, sub = tid & 3;
    int n = n0 + m;
    int e1 = rowptrL[n+1];
    const float* xb = xn_in + (size_t)b*Nn;
    float sx = 0.f;
    for (int e = rowptrL[n] + sub; e < e1; e += 4) sx += xb[srcsL[e]];
    sx += __shfl_xor(sx, 1); sx += __shfl_xor(sx, 2);
    if (sub == 0){
      int g = g0 + m;
      float xv = xn_in[g];
      float prea = pre_t[g] + invdegL[n]*W_nb[0]*sx + W_root[0]*xv;
      xn_lds[m] = xv;
      gcn_lds[m] = sigm(prea);
    }
  }
  __syncthreads();

  // --- stage x2 (slots 0..3): [xn, f0..f15, gcn, 0...] from bf16 xfb ---
  if (tid < MB){
    int row = tid;
    const bf16x8* xf = (const bf16x8*)&xfb_t[(size_t)(g0+row)*16];
    bf16x8 x0 = xf[0], x1 = xf[1];
    short v[32];
    v[0] = (short)f2bfu(xn_lds[row]);
    #pragma unroll
    for (int k = 0; k < 8; k++){ v[1+k] = x0[k]; v[9+k] = x1[k]; }
    v[17] = (short)f2bfu(gcn_lds[row]);
    #pragma unroll
    for (int k = 18; k < 32; k++) v[k] = 0;
    #pragma unroll
    for (int s = 0; s < 4; s++){
      int pos = (row + s) & 63;
      *(bf16x8*)&A_lds[(s*MB + pos)*8] = *(bf16x8*)&v[s*8];
    }
  }
  // --- stage h (slots 4..19): fp32 global -> bf16 LDS, coalesced 32B/thread ---
  for (int i = tid; i < MB*16; i += 256){
    int kg = i & 15, row = i >> 4;
    const float4* hp = (const float4*)&h[(size_t)(g0+row)*Hh + kg*8];
    float4 h0 = hp[0], h1 = hp[1];
    short hv[8];
    hv[0]=(short)f2bfu(h0.x); hv[1]=(short)f2bfu(h0.y); hv[2]=(short)f2bfu(h0.z); hv[3]=(short)f2bfu(h0.w);
    hv[4]=(short)f2bfu(h1.x); hv[5]=(short)f2bfu(h1.y); hv[6]=(short)f2bfu(h1.z); hv[7]=(short)f2bfu(h1.w);
    int s = 4 + kg, pos = (row + s) & 63;
    *(bf16x8*)&A_lds[(s*MB + pos)*8] = *(bf16x8*)&hv[0];
  }
  __syncthreads();

  const int l = tid & 63, w = tid >> 6;
  const int c = l & 15, lg = l >> 4;

  f32x4 acc[4][4][2] = {};   // [gate][m][nt]
  #pragma unroll
  for (int kk = 0; kk < 5; kk++){
    bf16x8 a[4];
    #pragma unroll
    for (int m = 0; m < 4; m++){
      int s = kk*4 + lg, row = m*16 + c, pos = (row + s) & 63;
      a[m] = *(const bf16x8*)&A_lds[(s*MB + pos)*8];
    }
    #pragma unroll
    for (int g = 0; g < 4; g++){
      #pragma unroll
      for (int nt = 0; nt < 2; nt++){
        const bf16x8 bv = *(const bf16x8*)&Wpack[ (size_t)((((g*4+w)*2+nt)*NSLOT + kk*4 + lg)*16 + c)*8 ];
        #pragma unroll
        for (int m = 0; m < 4; m++)
          acc[g][m][nt] = __builtin_amdgcn_mfma_f32_16x16x32_bf16(a[m], bv, acc[g][m][nt], 0, 0, 0);
      }
    }
  }

  // --- epilogue: register-local GRU elementwise, fp32 h carry ---
  float bR[2], bZ[2], bI[2], bH[2], wo[2]; int jj[2];
  #pragma unroll
  for (int nt = 0; nt < 2; nt++){
    int j = w*32 + nt*16 + c; jj[nt] = j;
    bR[nt] = b_ih[j] + b_hh[j];
    bZ[nt] = b_ih[128+j] + b_hh[128+j];
    bI[nt] = b_ih[256+j];
    bH[nt] = b_hh[256+j];
    wo[nt] = W_out[j];
  }
  float psum[4][4] = {};
  #pragma unroll
  for (int m = 0; m < 4; m++){
    #pragma unroll
    for (int nt = 0; nt < 2; nt++){
      #pragma unroll
      for (int q = 0; q < 4; q++){
        int row = 16*m + lg*4 + q;
        size_t off = (size_t)(g0 + row)*Hh + jj[nt];
        float hold = h[off];
        float rr = sigm(acc[0][m][nt][q] + bR[nt]);
        float zz = sigm(acc[1][m][nt][q] + bZ[nt]);
        float nn = tanh_f(acc[2][m][nt][q] + bI[nt] + rr*(acc[3][m][nt][q] + bH[nt]));
        float hv = (1.f - zz)*nn + zz*hold;
        h[off] = hv;
        psum[m][q] = fmaf(hv, wo[nt], psum[m][q]);
      }
    }
  }
  #pragma unroll
  for (int mask = 1; mask < 16; mask <<= 1){
    #pragma unroll
    for (int m = 0; m < 4; m++)
      #pragma unroll
      for (int q = 0; q < 4; q++)
        psum[m][q] += __shfl_xor(psum[m][q], mask);
  }
  if (c == 0){
    #pragma unroll
    for (int m = 0; m < 4; m++)
      #pragma unroll
      for (int q = 0; q < 4; q++)
        xnpart[w][16*m + lg*4 + q] = psum[m][q];
  }
  __syncthreads();
  if (tid < MB){
    int row = tid, g = g0 + row, n = n0 + row;
    float xv = xnpart[0][row] + xnpart[1][row] + xnpart[2][row] + xnpart[3][row] + b_out[0];
    xn_out[g] = xv;
    out[((size_t)b*FW + t)*Nn + n] = xv;
  }
}

extern "C" void kernel_launch(void* const* d_in, const int* in_sizes, int n_in,
                              void* d_out, int out_size, void* d_ws, size_t ws_size,
                              hipStream_t stream){
  const float* feature = (const float*)d_in[0];
  const float* pm25    = (const float*)d_in[1];
  const int*   eidx    = (const int*)d_in[2];
  const float* W_nb    = (const float*)d_in[3];
  const float* b_nb    = (const float*)d_in[4];
  const float* W_root  = (const float*)d_in[5];
  const float* W_ih    = (const float*)d_in[6];
  const float* W_hh    = (const float*)d_in[7];
  const float* b_ih    = (const float*)d_in[8];
  const float* b_hh    = (const float*)d_in[9];
  const float* W_out   = (const float*)d_in[10];
  const float* b_out   = (const float*)d_in[11];
  float* out = (float*)d_out;

  char* wsp = (char*)d_ws;
  float* invdegL = (float*)wsp; wsp += 512*4;
  int*   rowptrL = (int*)wsp;   wsp += 520*4;
  int*   srcsL   = (int*)wsp;   wsp += Ee*4;
  float* xn_a    = (float*)wsp; wsp += (size_t)BN*4;
  float* xn_b    = (float*)wsp; wsp += (size_t)BN*4;
  float* sfeat   = (float*)wsp; wsp += (size_t)FW*BN*4;
  float* pre     = (float*)wsp; wsp += (size_t)FW*BN*4;
  unsigned short* xfb = (unsigned short*)wsp; wsp += (size_t)FW*BN*16*2;
  unsigned short* Wpack = (unsigned short*)wsp; wsp += (size_t)WPN*2;
  float* hbuf    = (float*)wsp; wsp += (size_t)BN*Hh*4;

  hipMemsetAsync(hbuf, 0, (size_t)BN*Hh*sizeof(float), stream);

  k_csr    <<<1, 512, 0, stream>>>(eidx, rowptrL, srcsL, invdegL);
  k_init_xn<<<BN/256, 256, 0, stream>>>(pm25, xn_a);
  k_wpack  <<<(WPN+255)/256, 256, 0, stream>>>(W_ih, W_hh, Wpack);
  k_sfeat  <<<(FW*BN)/256, 256, 0, stream>>>(feature, W_nb, W_root, sfeat, pre, xfb);
  k_aggT   <<<(FW*BN)/256, 256, 0, stream>>>(rowptrL, srcsL, sfeat, invdegL, b_nb, pre);

  float* xa = xn_a; float* xb = xn_b;
  for (int t = 0; t < FW; t++){
    k_gru<<<BN/MB, 256, 0, stream>>>(hbuf, xa, xb, pre + (size_t)t*BN, invdegL,
                                     xfb + (size_t)t*BN*16, rowptrL, srcsL, Wpack,
                                     b_ih, b_hh, W_nb, W_root, W_out, b_out, out, t);
    float* tmp = xa; xa = xb; xb = tmp;
  }
}